// Round 14
// baseline (44.828 us; speedup 1.0000x reference)
//
#include <hip/hip_runtime.h>
#include <math.h>

#define BB 4096
#define CC 1024        // padded class count (1000 real + 24 pad)
#define DD 256

typedef __attribute__((ext_vector_type(4))) float f32x4;
typedef __attribute__((ext_vector_type(2))) float f32x2;
typedef __bf16 bf16x8 __attribute__((ext_vector_type(8)));
typedef unsigned short u16x8 __attribute__((ext_vector_type(8)));

// ---- workspace byte offsets ----
#define PART_B  (size_t)0              // [2][32][1024] float4: S,T,PP (1 MB)
#define CNTF_B  (size_t)1048576        // float[1024] class multiplicity
#define ENTL_B  (size_t)1052672        // float[512] per-block entl partials
#define ACC_B   (size_t)1054720        // double[2]
#define CNT_B   (size_t)1054736        // int: merge completion counter

#define CLIPV 0.99999f
#define LOG_EPS_C (-11.512925464970229f)   // ln(1e-5)
#define LN2F 0.6931471805599453f
#define PIF 3.14159265358979323846f

__device__ __forceinline__ unsigned short f2bf(float f) {
    unsigned u = __float_as_uint(f);
    u += 0x7fffu + ((u >> 16) & 1u);
    return (unsigned short)(u >> 16);
}

__device__ __forceinline__ bf16x8 cvt8(float4 a, float4 b, float& sq) {
    sq += a.x*a.x + a.y*a.y + a.z*a.z + a.w*a.w
        + b.x*b.x + b.y*b.y + b.z*b.z + b.w*b.w;
    u16x8 u;
    u[0] = f2bf(a.x); u[1] = f2bf(a.y); u[2] = f2bf(a.z); u[3] = f2bf(a.w);
    u[4] = f2bf(b.x); u[5] = f2bf(b.y); u[6] = f2bf(b.z); u[7] = f2bf(b.w);
    return __builtin_bit_cast(bf16x8, u);
}

__device__ __forceinline__ f32x2 splat2(float s) { return (f32x2){s, s}; }
__device__ __forceinline__ f32x2 emax2(f32x2 a, f32x2 b) { return __builtin_elementwise_max(a, b); }
__device__ __forceinline__ f32x2 emin2(f32x2 a, f32x2 b) { return __builtin_elementwise_min(a, b); }

// 16-lane-row sum reduction via DPP row rotates (pure VALU; no LDS pipe)
#define DPP_ROR_ADD(v, ctrl) \
    v += __builtin_bit_cast(float, __builtin_amdgcn_update_dpp( \
        0, __builtin_bit_cast(int, v), (ctrl), 0xf, 0xf, true))
__device__ __forceinline__ float rowsum16(float v) {
    DPP_ROR_ADD(v, 0x121);   // row_ror:1
    DPP_ROR_ADD(v, 0x122);   // row_ror:2
    DPP_ROR_ADD(v, 0x124);   // row_ror:4
    DPP_ROR_ADD(v, 0x128);   // row_ror:8
    return v;
}

// Fused: per-block fp32->bf16 conversion staging (reg-staged, T14 pattern),
// in-block row stats + label-scan counts, 128x128 MFMA tile, packed-f32
// elementwise, DPP reductions. Plain-store outputs; zero global atomics.
__launch_bounds__(512, 2)
__global__ void fused_kernel(const float* __restrict__ yimg, const float* __restrict__ ytxt,
                             const float* __restrict__ cw, const int* __restrict__ labels,
                             char* __restrict__ ws) {
    __shared__ unsigned short AhL[8192], BhL[8192];   // 16 KB each: [kg(8)][row(128)][8]
    __shared__ float4 rs0l[128];
    __shared__ float2 ysl[128];
    __shared__ float  cntl[128];
    __shared__ float  smrg[128][8];
    __shared__ float  sAtom[8];
    __shared__ float  xpart[512], ypart[512];

    const int tid = threadIdx.x;
    const int l = tid & 63;
    const int w = tid >> 6;                 // 0..7
    const int wm = w >> 1, wn = w & 1;      // 4x2 wave grid; 32x64 per wave
    const int bx = blockIdx.x, by = blockIdx.y, pair = blockIdx.z;
    const int rowbase = by * 128, colbase = bx * 128;
    const int lbid = bx + 32 * by + 256 * pair;

    if (tid < 128) cntl[tid] = 0.f;
    if (lbid == 0 && tid == 0) {
        *(int*)(ws + CNT_B) = 0;
        ((double*)(ws + ACC_B))[0] = 0.0;
        ((double*)(ws + ACC_B))[1] = 0.0;
    }

    // per-thread staging geometry: row rA, k-groups kg and kg+4
    const int rA = (w & 1) * 64 + l;               // local row 0..127
    const int gA = rowbase + rA;
    const float* Arow = cw + (size_t)(gA < 1000 ? gA : 0) * DD;  // pad rows alias class 0 (weight 0)
    const float* Y = pair ? ytxt : yimg;
    const float* Brow = Y + (size_t)(colbase + rA) * DD;
    const int kg = w >> 1;                         // 0..3
    const int wb0 = (kg * 128 + rA) * 16;          // LDS byte base; slice 2 at +8192

#define LOADC(c) do { \
        const float4* pa = (const float4*)(Arow + (c) * 64 + kg * 8); \
        ra[0] = pa[0]; ra[1] = pa[1]; ra[2] = pa[8]; ra[3] = pa[9]; \
        const float4* pb = (const float4*)(Brow + (c) * 64 + kg * 8); \
        rb[0] = pb[0]; rb[1] = pb[1]; rb[2] = pb[8]; rb[3] = pb[9]; \
    } while (0)

    float4 ra[4], rb[4];
    float x2p = 0.f, y2p = 0.f;
    LOADC(0);
    __syncthreads();                               // cntl init visible

    // label scan: 8 labels/thread -> LDS counts for this block's 128-class window
    {
        int4 la = ((const int4*)labels)[tid * 2];
        int4 lb = ((const int4*)labels)[tid * 2 + 1];
        int v;
        v = la.x - rowbase; if ((unsigned)v < 128u) atomicAdd(&cntl[v], 1.f);
        v = la.y - rowbase; if ((unsigned)v < 128u) atomicAdd(&cntl[v], 1.f);
        v = la.z - rowbase; if ((unsigned)v < 128u) atomicAdd(&cntl[v], 1.f);
        v = la.w - rowbase; if ((unsigned)v < 128u) atomicAdd(&cntl[v], 1.f);
        v = lb.x - rowbase; if ((unsigned)v < 128u) atomicAdd(&cntl[v], 1.f);
        v = lb.y - rowbase; if ((unsigned)v < 128u) atomicAdd(&cntl[v], 1.f);
        v = lb.z - rowbase; if ((unsigned)v < 128u) atomicAdd(&cntl[v], 1.f);
        v = lb.w - rowbase; if ((unsigned)v < 128u) atomicAdd(&cntl[v], 1.f);
    }

    f32x4 acc[2][4];
    #pragma unroll
    for (int i = 0; i < 2; ++i)
        #pragma unroll
        for (int j = 0; j < 4; ++j) acc[i][j] = (f32x4){0.f, 0.f, 0.f, 0.f};

    #pragma unroll
    for (int c = 0; c < 4; ++c) {
        if (c) __syncthreads();                    // prev chunk fully consumed
        // stage chunk c: convert + accumulate squares + ds_write (conflict-free rows)
        *(bf16x8*)((char*)AhL + wb0)        = cvt8(ra[0], ra[1], x2p);
        *(bf16x8*)((char*)AhL + wb0 + 8192) = cvt8(ra[2], ra[3], x2p);
        *(bf16x8*)((char*)BhL + wb0)        = cvt8(rb[0], rb[1], y2p);
        *(bf16x8*)((char*)BhL + wb0 + 8192) = cvt8(rb[2], rb[3], y2p);
        if (c < 3) LOADC(c + 1);                   // issue next loads early (T14)
        __syncthreads();                           // chunk c staged
        #pragma unroll
        for (int ks = 0; ks < 2; ++ks) {
            const int kgl = ks * 4 + (l >> 4);
            const int abyte = (kgl * 128 + wm * 32 + (l & 15)) * 16;
            const int bbyte = (kgl * 128 + wn * 64 + (l & 15)) * 16;
            bf16x8 ah[2], bh[4];
            #pragma unroll
            for (int mi = 0; mi < 2; ++mi)
                ah[mi] = *(const bf16x8*)((const char*)AhL + abyte + mi * 256);
            #pragma unroll
            for (int ni = 0; ni < 4; ++ni)
                bh[ni] = *(const bf16x8*)((const char*)BhL + bbyte + ni * 256);
            #pragma unroll
            for (int mi = 0; mi < 2; ++mi)
                #pragma unroll
                for (int ni = 0; ni < 4; ++ni)
                    acc[mi][ni] = __builtin_amdgcn_mfma_f32_16x16x32_bf16(ah[mi], bh[ni], acc[mi][ni], 0, 0, 0);
        }
    }

    // ---- row/col stats from conversion partials ----
    xpart[tid] = x2p; ypart[tid] = y2p;
    __syncthreads();
    if (tid < 128) {
        float x2 = xpart[tid] + xpart[tid + 128] + xpart[tid + 256] + xpart[tid + 384];
        float xn = sqrtf(x2);
        float invxn = 1.f / xn;
        float a = 0.1f * (1.f - x2) * invxn;
        a = fminf(fmaxf(a, -CLIPV), CLIPV);
        rs0l[tid] = make_float4(x2, xn, invxn + xn, asinf(a));
    } else if (tid < 256) {
        int cix = tid - 128;
        float y2 = ypart[cix] + ypart[cix + 128] + ypart[cix + 256] + ypart[cix + 384];
        ysl[cix] = make_float2(y2, __int_as_float(labels[colbase + cix]));
    }
    __syncthreads();

    // ---- elementwise (packed f32 pairs over ni), class rows weighted by cnt ----
    f32x2 entl2 = splat2(0.f);
    f32x2 y2p2[2], opy2p[2];
    int labyc[4];
    #pragma unroll
    for (int p = 0; p < 2; ++p) {
        float2 a = ysl[wn * 64 + (p * 2 + 0) * 16 + (l & 15)];
        float2 b = ysl[wn * 64 + (p * 2 + 1) * 16 + (l & 15)];
        y2p2[p] = (f32x2){a.x, b.x};
        opy2p[p] = (f32x2){1.f + a.x, 1.f + b.x};
        labyc[p * 2 + 0] = __float_as_int(a.y);
        labyc[p * 2 + 1] = __float_as_int(b.y);
    }
    #pragma unroll
    for (int mi = 0; mi < 2; ++mi) {
        #pragma unroll
        for (int rr = 0; rr < 4; ++rr) {
            int rl_ = wm * 32 + mi * 16 + (l >> 4) * 4 + rr;
            int cls = rowbase + rl_;
            float4 r0 = rs0l[rl_];
            float cntw = cntl[rl_];
            float x2 = r0.x, xn = r0.y, opx2i = r0.z, psi = r0.w;
            f32x2 x2py2[2], x2y2p1[2], xnopy2[2];
            #pragma unroll
            for (int p = 0; p < 2; ++p) {
                x2py2[p]  = y2p2[p] + x2;
                x2y2p1[p] = y2p2[p] * x2 + 1.f;
                xnopy2[p] = opy2p[p] * xn;
            }
            f32x2 S2 = splat2(0.f), T2 = splat2(0.f), PP2 = splat2(0.f), rowE = splat2(0.f);
            #pragma unroll
            for (int p = 0; p < 2; ++p) {
                bool pos0 = (cls == labyc[p * 2 + 0]);
                bool pos1 = (cls == labyc[p * 2 + 1]);
                f32x2 dotv = (f32x2){acc[mi][p * 2 + 0][rr], acc[mi][p * 2 + 1][rr]};
                f32x2 m2dot = dotv * -2.f;
                f32x2 d2 = x2py2[p] + m2dot;                    // ||x-y||^2
                f32x2 q2 = x2y2p1[p] + m2dot;                   // mobius denom
                f32x2 tt = emax2(d2 * q2, splat2(1e-30f));
                f32x2 rs = (f32x2){__builtin_amdgcn_rsqf(tt[0]), __builtin_amdgcn_rsqf(tt[1])};
                f32x2 s_ = tt * rs;                             // sqrt(q2*d2)
                // entailment E
                f32x2 numer = dotv * opx2i - xnopy2[p];
                f32x2 arg = numer * rs;
                f32x2 ax = emin2(__builtin_elementwise_abs(arg), splat2(CLIPV));
                f32x2 pl = ax * -0.0012624911f + 0.0066700901f;
                pl = pl * ax + -0.0170881256f;
                pl = pl * ax +  0.0308918810f;
                pl = pl * ax + -0.0501743046f;
                pl = pl * ax +  0.0889789874f;
                pl = pl * ax + -0.2145988016f;
                pl = pl * ax +  1.5707963050f;
                f32x2 om = 1.f - ax;
                f32x2 sq = (f32x2){sqrtf(om[0]), sqrtf(om[1])};
                f32x2 racos = sq * pl;
                f32x2 pmr = PIF - racos;
                f32x2 theta;
                theta[0] = (arg[0] < 0.f) ? pmr[0] : racos[0];
                theta[1] = (arg[1] < 0.f) ? pmr[1] : racos[1];
                f32x2 h = theta - psi;
                f32x2 g = emax2(h, splat2(0.f));
                f32x2 nc = emax2(1.f - g, splat2(0.f));
                f32x2 contrib;
                contrib[0] = pos0 ? g[0] : nc[0];
                contrib[1] = pos1 ? g[1] : nc[1];
                rowE += contrib;
                // dist + softmax: e = exp(-dist) = (q2e-s)/(q2e+s)
                f32x2 q2e = q2 + 1e-5f;
                f32x2 ne = q2e - s_;
                f32x2 de = q2e + s_;
                f32x2 rd = (f32x2){__builtin_amdgcn_rcpf(de[0]), __builtin_amdgcn_rcpf(de[1])};
                f32x2 e_ = ne * rd;
                f32x2 lu = (f32x2){__builtin_amdgcn_logf(e_[0]), __builtin_amdgcn_logf(e_[1])};
                f32x2 nd = lu * LN2F;                           // -dist
                S2 += e_;
                T2 = e_ * nd + T2;
                f32x2 pe;
                pe[0] = pos0 ? e_[0] : 0.f;
                pe[1] = pos1 ? e_[1] : 0.f;
                PP2 += pe;
            }
            entl2 = rowE * splat2(cntw) + entl2;    // weight by class multiplicity
            float S = rowsum16(S2[0] + S2[1]);
            float T = rowsum16(T2[0] + T2[1]);
            float PP = rowsum16(PP2[0] + PP2[1]);
            if ((l & 15) == 0) {
                smrg[rl_][wn * 4 + 0] = S; smrg[rl_][wn * 4 + 1] = T; smrg[rl_][wn * 4 + 2] = PP;
            }
        }
    }
    __syncthreads();
    if (tid < 128) {
        float4 o;
        o.x = smrg[tid][0] + smrg[tid][4];
        o.y = smrg[tid][1] + smrg[tid][5];
        o.z = smrg[tid][2] + smrg[tid][6];
        o.w = 0.f;
        ((float4*)(ws + PART_B))[((size_t)pair * 32 + bx) * CC + rowbase + tid] = o;
        if (pair == 0 && bx == 0)
            ((float*)(ws + CNTF_B))[rowbase + tid] = cntl[tid];
    }
    float entl = entl2[0] + entl2[1];
    #pragma unroll
    for (int off = 32; off > 0; off >>= 1) entl += __shfl_xor(entl, off);
    if (l == 0) sAtom[w] = entl;
    __syncthreads();
    if (tid == 0) {
        float tot = 0.f;
        #pragma unroll
        for (int i = 0; i < 8; ++i) tot += sAtom[i];
        ((float*)(ws + ENTL_B))[lbid] = tot;       // plain store; merge block 0 sums
    }
#undef LOADC
}

// merge + finalize: 4 blocks x 512. Block 0 also reduces the 512 entl partials.
__global__ void merge_kernel(char* __restrict__ ws, float* __restrict__ out) {
    __shared__ double sbufd[8];
    __shared__ float  sbufe[8];
    const int bid = blockIdx.x, tid = threadIdx.x;
    const int l = tid & 63, w = tid >> 6;
    int idx = bid * 512 + tid;                    // 0..2047
    int pr = idx >> 10, c = idx & 1023;
    const float4* part = (const float4*)(ws + PART_B) + (size_t)pr * 32 * CC + c;
    float S = 0.f, T = 0.f, PP = 0.f;
    #pragma unroll 4
    for (int cb = 0; cb < 32; ++cb) {
        float4 v = part[(size_t)cb * CC];
        S += v.x; T += v.y; PP += v.z;
    }
    float wgt = ((const float*)(ws + CNTF_B))[c];
    float logc = logf(1.0f / wgt + 1e-5f);        // inf for wgt==0, guarded below
    float invS = 1.f / S;
    float fp = PP * invS;
    float rl = T * invS - logf(S) - fp * logc - (1.f - fp) * LOG_EPS_C;
    double dv = (wgt > 0.f) ? (double)(rl * wgt) : 0.0;
    #pragma unroll
    for (int off = 32; off > 0; off >>= 1) dv += __shfl_down(dv, off);
    if (l == 0) sbufd[w] = dv;
    float ev = (bid == 0) ? ((const float*)(ws + ENTL_B))[tid] : 0.f;
    #pragma unroll
    for (int off = 32; off > 0; off >>= 1) ev += __shfl_down(ev, off);
    if (l == 0) sbufe[w] = ev;
    __syncthreads();
    if (tid == 0) {
        double* accum = (double*)(ws + ACC_B);
        double dt = 0.0; float et = 0.f;
        #pragma unroll
        for (int i = 0; i < 8; ++i) { dt += sbufd[i]; et += sbufe[i]; }
        atomicAdd(&accum[1], dt);
        if (bid == 0) atomicAdd(&accum[0], (double)et);
        __threadfence();
        int old = atomicAdd((int*)(ws + CNT_B), 1);
        if (old == 3) {                            // last block: finalize
            __threadfence();
            float e = (float)accum[0];
            float h = (float)(accum[1] * (1.0 / 4096.0));
            out[0] = e;
            out[1] = h;
            out[2] = e + h;
        }
    }
}

extern "C" void kernel_launch(void* const* d_in, const int* in_sizes, int n_in,
                              void* d_out, int out_size, void* d_ws, size_t ws_size,
                              hipStream_t stream) {
    (void)in_sizes; (void)n_in; (void)out_size; (void)ws_size;
    const float* img = (const float*)d_in[0];
    const float* txt = (const float*)d_in[1];
    const float* cw  = (const float*)d_in[2];
    const int* labels = (const int*)d_in[3];
    float* out = (float*)d_out;
    char* wsb = (char*)d_ws;

    fused_kernel<<<dim3(32, 8, 2), 512, 0, stream>>>(img, txt, cw, labels, wsb);
    merge_kernel<<<4, 512, 0, stream>>>(wsb, out);
}

// Round 15
// 35.455 us; speedup vs baseline: 1.2644x; 1.2644x over previous
//
#include <hip/hip_runtime.h>
#include <math.h>

#define BB 4096
#define CC 1024        // padded class count (1000 real + 24 pad)
#define DD 256

typedef __attribute__((ext_vector_type(4))) float f32x4;
typedef __attribute__((ext_vector_type(2))) float f32x2;
typedef __bf16 bf16x8 __attribute__((ext_vector_type(8)));

// ---- workspace byte offsets ----
#define PART_B  (size_t)0              // [2][32][1024] float4: S,T,PP (1 MB)
#define CNTF_B  (size_t)1048576        // float[1024] class multiplicity
#define ENTL_B  (size_t)1052672        // float[512] per-block entl partials
#define ACC_B   (size_t)1054720        // double[2]
#define CNT_B   (size_t)1054736        // int: merge completion counter

#define CLIPV 0.99999f
#define LOG_EPS_C (-11.512925464970229f)   // ln(1e-5)
#define LN2F 0.6931471805599453f
#define PIF 3.14159265358979323846f

__device__ __forceinline__ ushort4 cvt4(float4 a, float& sq) {
    sq += a.x*a.x + a.y*a.y + a.z*a.z + a.w*a.w;
    __bf16 b0 = (__bf16)a.x, b1 = (__bf16)a.y, b2 = (__bf16)a.z, b3 = (__bf16)a.w;
    ushort4 u;
    u.x = __builtin_bit_cast(unsigned short, b0);
    u.y = __builtin_bit_cast(unsigned short, b1);
    u.z = __builtin_bit_cast(unsigned short, b2);
    u.w = __builtin_bit_cast(unsigned short, b3);
    return u;
}

__device__ __forceinline__ f32x2 splat2(float s) { return (f32x2){s, s}; }
__device__ __forceinline__ f32x2 emax2(f32x2 a, f32x2 b) { return __builtin_elementwise_max(a, b); }
__device__ __forceinline__ f32x2 emin2(f32x2 a, f32x2 b) { return __builtin_elementwise_min(a, b); }

// 16-lane-row sum reduction via DPP row rotates (pure VALU; no LDS pipe)
#define DPP_ROR_ADD(v, ctrl) \
    v += __builtin_bit_cast(float, __builtin_amdgcn_update_dpp( \
        0, __builtin_bit_cast(int, v), (ctrl), 0xf, 0xf, true))
__device__ __forceinline__ float rowsum16(float v) {
    DPP_ROR_ADD(v, 0x121);   // row_ror:1
    DPP_ROR_ADD(v, 0x122);   // row_ror:2
    DPP_ROR_ADD(v, 0x124);   // row_ror:4
    DPP_ROR_ADD(v, 0x128);   // row_ror:8
    return v;
}

// Fused: per-block fp32->bf16 conversion staging (coalesced: 4 threads/row,
// 64B-contiguous per 4-lane group), in-block row stats + label-scan counts,
// 128x128 MFMA tile, packed-f32 elementwise, DPP reductions.
__launch_bounds__(512, 2)
__global__ void fused_kernel(const float* __restrict__ yimg, const float* __restrict__ ytxt,
                             const float* __restrict__ cw, const int* __restrict__ labels,
                             char* __restrict__ ws) {
    __shared__ unsigned short AhL[8192], BhL[8192];   // 16 KB each: [kg(8)][row(128)][8]
    __shared__ float4 rs0l[128];
    __shared__ float2 ysl[128];
    __shared__ float  cntl[128];
    __shared__ float  smrg[128][8];
    __shared__ float  sAtom[8];
    __shared__ float  xpart[512], ypart[512];

    const int tid = threadIdx.x;
    const int l = tid & 63;
    const int w = tid >> 6;                 // 0..7
    const int wm = w >> 1, wn = w & 1;      // 4x2 wave grid; 32x64 per wave
    const int bx = blockIdx.x, by = blockIdx.y, pair = blockIdx.z;
    const int rowbase = by * 128, colbase = bx * 128;
    const int lbid = bx + 32 * by + 256 * pair;

    if (tid < 128) cntl[tid] = 0.f;
    if (lbid == 0 && tid == 0) {
        *(int*)(ws + CNT_B) = 0;
        ((double*)(ws + ACC_B))[0] = 0.0;
        ((double*)(ws + ACC_B))[1] = 0.0;
    }

    // staging geometry: 4 threads per row; thread covers quarter q of each chunk row
    const int row = tid >> 2;              // 0..127
    const int q = tid & 3;
    const int gA = rowbase + row;
    const float4* Af4 = (const float4*)(cw + (size_t)(gA < 1000 ? gA : 0) * DD);  // pad alias cls 0 (wgt 0)
    const float* Y = pair ? ytxt : yimg;
    const float4* Bf4 = (const float4*)(Y + (size_t)(colbase + row) * DD);

#define LOADC(c) do { \
        _Pragma("unroll") for (int j = 0; j < 4; ++j) ra[j] = Af4[(c) * 16 + q + 4 * j]; \
        _Pragma("unroll") for (int j = 0; j < 4; ++j) rb[j] = Bf4[(c) * 16 + q + 4 * j]; \
    } while (0)
// write float4 j of this thread into [kg][row][slot] layout (8B pieces)
#define STOREC() do { \
        _Pragma("unroll") for (int j = 0; j < 4; ++j) { \
            int f4i = q + 4 * j; \
            *(ushort4*)((char*)AhL + (((f4i >> 1) * 128 + row) << 4) + ((f4i & 1) << 3)) = cvt4(ra[j], x2p); \
            *(ushort4*)((char*)BhL + (((f4i >> 1) * 128 + row) << 4) + ((f4i & 1) << 3)) = cvt4(rb[j], y2p); \
        } \
    } while (0)

    float4 ra[4], rb[4];
    float x2p = 0.f, y2p = 0.f;
    LOADC(0);
    __syncthreads();                               // cntl init visible

    // label scan: 8 labels/thread -> LDS counts for this block's 128-class window
    {
        int4 la = ((const int4*)labels)[tid * 2];
        int4 lb = ((const int4*)labels)[tid * 2 + 1];
        int v;
        v = la.x - rowbase; if ((unsigned)v < 128u) atomicAdd(&cntl[v], 1.f);
        v = la.y - rowbase; if ((unsigned)v < 128u) atomicAdd(&cntl[v], 1.f);
        v = la.z - rowbase; if ((unsigned)v < 128u) atomicAdd(&cntl[v], 1.f);
        v = la.w - rowbase; if ((unsigned)v < 128u) atomicAdd(&cntl[v], 1.f);
        v = lb.x - rowbase; if ((unsigned)v < 128u) atomicAdd(&cntl[v], 1.f);
        v = lb.y - rowbase; if ((unsigned)v < 128u) atomicAdd(&cntl[v], 1.f);
        v = lb.z - rowbase; if ((unsigned)v < 128u) atomicAdd(&cntl[v], 1.f);
        v = lb.w - rowbase; if ((unsigned)v < 128u) atomicAdd(&cntl[v], 1.f);
    }

    f32x4 acc[2][4];
    #pragma unroll
    for (int i = 0; i < 2; ++i)
        #pragma unroll
        for (int j = 0; j < 4; ++j) acc[i][j] = (f32x4){0.f, 0.f, 0.f, 0.f};

    #pragma unroll
    for (int c = 0; c < 4; ++c) {
        if (c) __syncthreads();                    // prev chunk fully consumed
        STOREC();                                  // convert + squares + ds_write
        if (c < 3) LOADC(c + 1);                   // issue next loads early (T14)
        __syncthreads();                           // chunk c staged
        #pragma unroll
        for (int ks = 0; ks < 2; ++ks) {
            const int kgl = ks * 4 + (l >> 4);
            const int abyte = (kgl * 128 + wm * 32 + (l & 15)) * 16;
            const int bbyte = (kgl * 128 + wn * 64 + (l & 15)) * 16;
            bf16x8 ah[2], bh[4];
            #pragma unroll
            for (int mi = 0; mi < 2; ++mi)
                ah[mi] = *(const bf16x8*)((const char*)AhL + abyte + mi * 256);
            #pragma unroll
            for (int ni = 0; ni < 4; ++ni)
                bh[ni] = *(const bf16x8*)((const char*)BhL + bbyte + ni * 256);
            #pragma unroll
            for (int mi = 0; mi < 2; ++mi)
                #pragma unroll
                for (int ni = 0; ni < 4; ++ni)
                    acc[mi][ni] = __builtin_amdgcn_mfma_f32_16x16x32_bf16(ah[mi], bh[ni], acc[mi][ni], 0, 0, 0);
        }
    }

    // ---- row/col stats from conversion partials (4 partials per row) ----
    xpart[tid] = x2p; ypart[tid] = y2p;
    __syncthreads();
    if (tid < 128) {
        float x2 = xpart[tid * 4] + xpart[tid * 4 + 1] + xpart[tid * 4 + 2] + xpart[tid * 4 + 3];
        float xn = sqrtf(x2);
        float invxn = 1.f / xn;
        float a = 0.1f * (1.f - x2) * invxn;
        a = fminf(fmaxf(a, -CLIPV), CLIPV);
        rs0l[tid] = make_float4(x2, xn, invxn + xn, asinf(a));
    } else if (tid < 256) {
        int cix = tid - 128;
        float y2 = ypart[cix * 4] + ypart[cix * 4 + 1] + ypart[cix * 4 + 2] + ypart[cix * 4 + 3];
        ysl[cix] = make_float2(y2, __int_as_float(labels[colbase + cix]));
    }
    __syncthreads();

    // ---- elementwise (packed f32 pairs over ni), class rows weighted by cnt ----
    f32x2 entl2 = splat2(0.f);
    f32x2 y2p2[2], opy2p[2];
    int labyc[4];
    #pragma unroll
    for (int p = 0; p < 2; ++p) {
        float2 a = ysl[wn * 64 + (p * 2 + 0) * 16 + (l & 15)];
        float2 b = ysl[wn * 64 + (p * 2 + 1) * 16 + (l & 15)];
        y2p2[p] = (f32x2){a.x, b.x};
        opy2p[p] = (f32x2){1.f + a.x, 1.f + b.x};
        labyc[p * 2 + 0] = __float_as_int(a.y);
        labyc[p * 2 + 1] = __float_as_int(b.y);
    }
    #pragma unroll
    for (int mi = 0; mi < 2; ++mi) {
        #pragma unroll
        for (int rr = 0; rr < 4; ++rr) {
            int rl_ = wm * 32 + mi * 16 + (l >> 4) * 4 + rr;
            int cls = rowbase + rl_;
            float4 r0 = rs0l[rl_];
            float cntw = cntl[rl_];
            float x2 = r0.x, xn = r0.y, opx2i = r0.z, psi = r0.w;
            f32x2 x2py2[2], x2y2p1[2], xnopy2[2];
            #pragma unroll
            for (int p = 0; p < 2; ++p) {
                x2py2[p]  = y2p2[p] + x2;
                x2y2p1[p] = y2p2[p] * x2 + 1.f;
                xnopy2[p] = opy2p[p] * xn;
            }
            f32x2 S2 = splat2(0.f), T2 = splat2(0.f), PP2 = splat2(0.f), rowE = splat2(0.f);
            #pragma unroll
            for (int p = 0; p < 2; ++p) {
                bool pos0 = (cls == labyc[p * 2 + 0]);
                bool pos1 = (cls == labyc[p * 2 + 1]);
                f32x2 dotv = (f32x2){acc[mi][p * 2 + 0][rr], acc[mi][p * 2 + 1][rr]};
                f32x2 m2dot = dotv * -2.f;
                f32x2 d2 = x2py2[p] + m2dot;                    // ||x-y||^2
                f32x2 q2 = x2y2p1[p] + m2dot;                   // mobius denom
                f32x2 tt = emax2(d2 * q2, splat2(1e-30f));
                f32x2 rs = (f32x2){__builtin_amdgcn_rsqf(tt[0]), __builtin_amdgcn_rsqf(tt[1])};
                f32x2 s_ = tt * rs;                             // sqrt(q2*d2)
                // entailment E
                f32x2 numer = dotv * opx2i - xnopy2[p];
                f32x2 arg = numer * rs;
                f32x2 ax = emin2(__builtin_elementwise_abs(arg), splat2(CLIPV));
                f32x2 pl = ax * -0.0012624911f + 0.0066700901f;
                pl = pl * ax + -0.0170881256f;
                pl = pl * ax +  0.0308918810f;
                pl = pl * ax + -0.0501743046f;
                pl = pl * ax +  0.0889789874f;
                pl = pl * ax + -0.2145988016f;
                pl = pl * ax +  1.5707963050f;
                f32x2 om = 1.f - ax;
                f32x2 sq = (f32x2){sqrtf(om[0]), sqrtf(om[1])};
                f32x2 racos = sq * pl;
                f32x2 pmr = PIF - racos;
                f32x2 theta;
                theta[0] = (arg[0] < 0.f) ? pmr[0] : racos[0];
                theta[1] = (arg[1] < 0.f) ? pmr[1] : racos[1];
                f32x2 h = theta - psi;
                f32x2 g = emax2(h, splat2(0.f));
                f32x2 nc = emax2(1.f - g, splat2(0.f));
                f32x2 contrib;
                contrib[0] = pos0 ? g[0] : nc[0];
                contrib[1] = pos1 ? g[1] : nc[1];
                rowE += contrib;
                // dist + softmax: e = exp(-dist) = (q2e-s)/(q2e+s)
                f32x2 q2e = q2 + 1e-5f;
                f32x2 ne = q2e - s_;
                f32x2 de = q2e + s_;
                f32x2 rd = (f32x2){__builtin_amdgcn_rcpf(de[0]), __builtin_amdgcn_rcpf(de[1])};
                f32x2 e_ = ne * rd;
                f32x2 lu = (f32x2){__builtin_amdgcn_logf(e_[0]), __builtin_amdgcn_logf(e_[1])};
                f32x2 nd = lu * LN2F;                           // -dist
                S2 += e_;
                T2 = e_ * nd + T2;
                f32x2 pe;
                pe[0] = pos0 ? e_[0] : 0.f;
                pe[1] = pos1 ? e_[1] : 0.f;
                PP2 += pe;
            }
            entl2 = rowE * splat2(cntw) + entl2;    // weight by class multiplicity
            float S = rowsum16(S2[0] + S2[1]);
            float T = rowsum16(T2[0] + T2[1]);
            float PP = rowsum16(PP2[0] + PP2[1]);
            if ((l & 15) == 0) {
                smrg[rl_][wn * 4 + 0] = S; smrg[rl_][wn * 4 + 1] = T; smrg[rl_][wn * 4 + 2] = PP;
            }
        }
    }
    __syncthreads();
    if (tid < 128) {
        float4 o;
        o.x = smrg[tid][0] + smrg[tid][4];
        o.y = smrg[tid][1] + smrg[tid][5];
        o.z = smrg[tid][2] + smrg[tid][6];
        o.w = 0.f;
        ((float4*)(ws + PART_B))[((size_t)pair * 32 + bx) * CC + rowbase + tid] = o;
        if (pair == 0 && bx == 0)
            ((float*)(ws + CNTF_B))[rowbase + tid] = cntl[tid];
    }
    float entl = entl2[0] + entl2[1];
    #pragma unroll
    for (int off = 32; off > 0; off >>= 1) entl += __shfl_xor(entl, off);
    if (l == 0) sAtom[w] = entl;
    __syncthreads();
    if (tid == 0) {
        float tot = 0.f;
        #pragma unroll
        for (int i = 0; i < 8; ++i) tot += sAtom[i];
        ((float*)(ws + ENTL_B))[lbid] = tot;       // plain store; merge block 0 sums
    }
#undef LOADC
#undef STOREC
}

// merge + finalize: 4 blocks x 512. Block 0 also reduces the 512 entl partials.
__global__ void merge_kernel(char* __restrict__ ws, float* __restrict__ out) {
    __shared__ double sbufd[8];
    __shared__ float  sbufe[8];
    const int bid = blockIdx.x, tid = threadIdx.x;
    const int l = tid & 63, w = tid >> 6;
    int idx = bid * 512 + tid;                    // 0..2047
    int pr = idx >> 10, c = idx & 1023;
    const float4* part = (const float4*)(ws + PART_B) + (size_t)pr * 32 * CC + c;
    float S = 0.f, T = 0.f, PP = 0.f;
    #pragma unroll 4
    for (int cb = 0; cb < 32; ++cb) {
        float4 v = part[(size_t)cb * CC];
        S += v.x; T += v.y; PP += v.z;
    }
    float wgt = ((const float*)(ws + CNTF_B))[c];
    float logc = logf(1.0f / wgt + 1e-5f);        // inf for wgt==0, guarded below
    float invS = 1.f / S;
    float fp = PP * invS;
    float rl = T * invS - logf(S) - fp * logc - (1.f - fp) * LOG_EPS_C;
    double dv = (wgt > 0.f) ? (double)(rl * wgt) : 0.0;
    #pragma unroll
    for (int off = 32; off > 0; off >>= 1) dv += __shfl_down(dv, off);
    if (l == 0) sbufd[w] = dv;
    float ev = (bid == 0) ? ((const float*)(ws + ENTL_B))[tid] : 0.f;
    #pragma unroll
    for (int off = 32; off > 0; off >>= 1) ev += __shfl_down(ev, off);
    if (l == 0) sbufe[w] = ev;
    __syncthreads();
    if (tid == 0) {
        double* accum = (double*)(ws + ACC_B);
        double dt = 0.0; float et = 0.f;
        #pragma unroll
        for (int i = 0; i < 8; ++i) { dt += sbufd[i]; et += sbufe[i]; }
        atomicAdd(&accum[1], dt);
        if (bid == 0) atomicAdd(&accum[0], (double)et);
        __threadfence();
        int old = atomicAdd((int*)(ws + CNT_B), 1);
        if (old == 3) {                            // last block: finalize
            __threadfence();
            float e = (float)accum[0];
            float h = (float)(accum[1] * (1.0 / 4096.0));
            out[0] = e;
            out[1] = h;
            out[2] = e + h;
        }
    }
}

extern "C" void kernel_launch(void* const* d_in, const int* in_sizes, int n_in,
                              void* d_out, int out_size, void* d_ws, size_t ws_size,
                              hipStream_t stream) {
    (void)in_sizes; (void)n_in; (void)out_size; (void)ws_size;
    const float* img = (const float*)d_in[0];
    const float* txt = (const float*)d_in[1];
    const float* cw  = (const float*)d_in[2];
    const int* labels = (const int*)d_in[3];
    float* out = (float*)d_out;
    char* wsb = (char*)d_ws;

    fused_kernel<<<dim3(32, 8, 2), 512, 0, stream>>>(img, txt, cw, labels, wsb);
    merge_kernel<<<4, 512, 0, stream>>>(wsb, out);
}